// Round 1
// baseline (342.942 us; speedup 1.0000x reference)
//
#include <hip/hip_runtime.h>

// VariationalLSTM: B=65536, T=24, H=64, gates=256, out=2.
// 512 WGs x 256 threads (4 waves). Each WG: 8 blocks of 16 batch rows.
// Wave w owns gate cols n = 16w + 64j + lane.lo (j=gate type i,f,g,o),
// i.e. units [16w,16w+16) for all 4 gate types.
// MFMA 16x16x32 bf16: A = h fragments (LDS round-trip), B = weight frags in VGPRs.
// c-state and activations stay fp32.

typedef short short8 __attribute__((ext_vector_type(8)));
typedef float f32x4 __attribute__((ext_vector_type(4)));

#define LOG2E 1.44269504088896340736f

__device__ inline float fsig(float x){
  float e = __builtin_amdgcn_exp2f(-LOG2E * x);
  return __builtin_amdgcn_rcpf(1.0f + e);
}
__device__ inline float ftanh(float x){
  float e = __builtin_amdgcn_exp2f((2.0f * LOG2E) * x);
  return 1.0f - 2.0f * __builtin_amdgcn_rcpf(1.0f + e);
}
__device__ inline unsigned short bf16c(float f){  // RNE f32->bf16
  unsigned uu = __builtin_bit_cast(unsigned, f);
  uu = (uu + 0x7fffu + ((uu >> 16) & 1u)) >> 16;
  return (unsigned short)uu;
}

__global__ __launch_bounds__(256, 2) void vlstm_kernel(
    const float* __restrict__ x,
    const float* __restrict__ Wih1, const float* __restrict__ Whh1,
    const float* __restrict__ bih1, const float* __restrict__ bhh1,
    const float* __restrict__ Wih2, const float* __restrict__ Whh2,
    const float* __restrict__ bih2, const float* __restrict__ bhh2,
    const float* __restrict__ Wout, const float* __restrict__ bout,
    const float* __restrict__ h10, const float* __restrict__ c10,
    const float* __restrict__ h20, const float* __restrict__ c20,
    const float* __restrict__ mt1v, const float* __restrict__ mt2v,
    const float* __restrict__ ml1v, const float* __restrict__ ml2v,
    float* __restrict__ out)
{
  // LDS: bf16 h tiles [16 rows][64 units], XOR-swizzled; fp32 final-h2 tile; x stage.
  __shared__ unsigned short sh1L[1024];  // h1 * m_layer1          (layer2 A input)
  __shared__ unsigned short sh1T[1024];  // h1 * m_layer1 * m_time1 (next-step layer1 A)
  __shared__ unsigned short sh2T[1024];  // h2 * m_layer2 * m_time2 (next-step layer2 A)
  __shared__ float h2f[1024];            // final h2 (fp32) for output reduction
  __shared__ float xlds[384];            // x tile transposed [24][16]

  const int tid = threadIdx.x;
  const int w  = tid >> 6;     // wave id 0..3
  const int l  = tid & 63;
  const int hi = l >> 4;       // 0..3
  const int lo = l & 15;
  const int u  = 16 * w + lo;  // unit column owned in D layout

  // ---- one-time: biases, x-coefficients, weight fragments (registers) ----
  float b1v[4], b2v[4], wiv[4];
  short8 fr1[4][2], frI[4][2], frH[4][2];
#pragma unroll
  for (int j = 0; j < 4; ++j){
    int n = u + 64 * j;                  // gate row in W matrices
    b1v[j] = bih1[n] + bhh1[n];
    b2v[j] = bih2[n] + bhh2[n];
    wiv[j] = Wih1[n];
#pragma unroll
    for (int kk = 0; kk < 2; ++kk){
      // B-frag: lane reads W[n][32kk + 8hi + e], e=0..7 (8 contiguous f32)
      int off = n * 64 + 32 * kk + 8 * hi;
      short8 s;
#pragma unroll
      for (int e = 0; e < 8; ++e) s[e] = (short)bf16c(Whh1[off + e]);
      fr1[j][kk] = s;
#pragma unroll
      for (int e = 0; e < 8; ++e) s[e] = (short)bf16c(Wih2[off + e]);
      frI[j][kk] = s;
#pragma unroll
      for (int e = 0; e < 8; ++e) s[e] = (short)bf16c(Whh2[off + e]);
      frH[j][kk] = s;
    }
  }

  // ---- LDS offsets (ushort indices), XOR swizzle byte ^= (m&7)<<4 ----
  int wIdx[4];                 // D-layout writes: rows m = 4hi + r, col u
#pragma unroll
  for (int r = 0; r < 4; ++r){
    int m = 4 * hi + r;
    wIdx[r] = ((m * 128 + u * 2) ^ ((m & 7) << 4)) >> 1;
  }
  int rIdx[2];                 // A-frag reads: m = lane&15, k = 32kk + 8hi + e
#pragma unroll
  for (int kk = 0; kk < 2; ++kk){
    int m = lo;
    rIdx[kk] = ((m * 128 + kk * 64 + hi * 16) ^ ((m & 7) << 4)) >> 1;
  }

  const int wg = blockIdx.x;
#pragma unroll 1
  for (int blk = 0; blk < 8; ++blk){
    const int row0 = wg * 128 + blk * 16;

    // ---- block init: x stage + states/masks + initial A tiles ----
    for (int idx = tid; idx < 384; idx += 256){
      int r = idx / 24, tt = idx - r * 24;
      xlds[tt * 16 + r] = x[(row0 + r) * 24 + tt];
    }
    float c1r[4], c2r[4], ml1r[4], ml2r[4], mt1r[4], mt2r[4];
#pragma unroll
    for (int r = 0; r < 4; ++r){
      int gofs = (row0 + 4 * hi + r) * 64 + u;
      c1r[r]  = c10[gofs];  c2r[r]  = c20[gofs];
      ml1r[r] = ml1v[gofs]; ml2r[r] = ml2v[gofs];
      mt1r[r] = mt1v[gofs]; mt2r[r] = mt2v[gofs];
      sh1T[wIdx[r]] = bf16c(h10[gofs] * mt1r[r]);   // t=0: h1_0 * m_time1
      sh2T[wIdx[r]] = bf16c(h20[gofs] * mt2r[r]);   // t=0: h2_0 * m_time2
    }
    __syncthreads();

    short8 a1[2], at2[2];
    a1[0]  = *(const short8*)&sh1T[rIdx[0]];
    a1[1]  = *(const short8*)&sh1T[rIdx[1]];
    at2[0] = *(const short8*)&sh2T[rIdx[0]];
    at2[1] = *(const short8*)&sh2T[rIdx[1]];

#pragma unroll 1
    for (int t = 0; t < 24; ++t){
      float xv[4];
#pragma unroll
      for (int r = 0; r < 4; ++r) xv[r] = xlds[t * 16 + 4 * hi + r];

      // ---- layer 1 gates ----
      f32x4 gt[4];
#pragma unroll
      for (int j = 0; j < 4; ++j){
        f32x4 acc;
#pragma unroll
        for (int r = 0; r < 4; ++r) acc[r] = fmaf(xv[r], wiv[j], b1v[j]);
        acc = __builtin_amdgcn_mfma_f32_16x16x32_bf16(a1[0], fr1[j][0], acc, 0, 0, 0);
        acc = __builtin_amdgcn_mfma_f32_16x16x32_bf16(a1[1], fr1[j][1], acc, 0, 0, 0);
        gt[j] = acc;
      }
#pragma unroll
      for (int r = 0; r < 4; ++r){
        float ti = fsig(gt[0][r]);
        float tf = fsig(gt[1][r]);
        float tg = ftanh(gt[2][r]);
        float to = fsig(gt[3][r]);
        float cn = fmaf(tf, c1r[r], ti * tg);
        c1r[r] = cn;
        float h1l = to * ftanh(cn) * ml1r[r];
        sh1L[wIdx[r]] = bf16c(h1l);
        sh1T[wIdx[r]] = bf16c(h1l * mt1r[r]);
      }
      __syncthreads();

      short8 a2[2];
      a2[0] = *(const short8*)&sh1L[rIdx[0]];
      a2[1] = *(const short8*)&sh1L[rIdx[1]];
      a1[0] = *(const short8*)&sh1T[rIdx[0]];   // for next step's layer 1
      a1[1] = *(const short8*)&sh1T[rIdx[1]];

      // ---- layer 2 gates ----
#pragma unroll
      for (int j = 0; j < 4; ++j){
        f32x4 acc;
#pragma unroll
        for (int r = 0; r < 4; ++r) acc[r] = b2v[j];
        acc = __builtin_amdgcn_mfma_f32_16x16x32_bf16(a2[0],  frI[j][0], acc, 0, 0, 0);
        acc = __builtin_amdgcn_mfma_f32_16x16x32_bf16(a2[1],  frI[j][1], acc, 0, 0, 0);
        acc = __builtin_amdgcn_mfma_f32_16x16x32_bf16(at2[0], frH[j][0], acc, 0, 0, 0);
        acc = __builtin_amdgcn_mfma_f32_16x16x32_bf16(at2[1], frH[j][1], acc, 0, 0, 0);
        gt[j] = acc;
      }
#pragma unroll
      for (int r = 0; r < 4; ++r){
        float ti = fsig(gt[0][r]);
        float tf = fsig(gt[1][r]);
        float tg = ftanh(gt[2][r]);
        float to = fsig(gt[3][r]);
        float cn = fmaf(tf, c2r[r], ti * tg);
        c2r[r] = cn;
        float h2l = to * ftanh(cn) * ml2r[r];
        sh2T[wIdx[r]] = bf16c(h2l * mt2r[r]);
        if (t == 23) h2f[(4 * hi + r) * 64 + u] = h2l;  // fp32 final h2
      }
      __syncthreads();

      at2[0] = *(const short8*)&sh2T[rIdx[0]];
      at2[1] = *(const short8*)&sh2T[rIdx[1]];
    }

    // ---- output: out[row][o] = sum_u h2f[row][u]*Wout[o][u] + bout[o] ----
    if (tid < 32){
      int r = tid & 15, o = tid >> 4;
      float acc = bout[o];
#pragma unroll 8
      for (int uu = 0; uu < 64; ++uu)
        acc = fmaf(h2f[r * 64 + uu], Wout[o * 64 + uu], acc);
      out[(row0 + r) * 2 + o] = acc;
    }
    __syncthreads();  // protect LDS tiles before next block's init writes
  }
}

extern "C" void kernel_launch(void* const* d_in, const int* in_sizes, int n_in,
                              void* d_out, int out_size, void* d_ws, size_t ws_size,
                              hipStream_t stream)
{
  // input order per setup_inputs(): x, W_ih1, W_hh1, b_ih1, b_hh1, W_ih2, W_hh2,
  // b_ih2, b_hh2, W_out, b_out, h1_0, c1_0, h2_0, c2_0, m_time1, m_time2, m_layer1, m_layer2
  vlstm_kernel<<<dim3(512), dim3(256), 0, stream>>>(
      (const float*)d_in[0],  (const float*)d_in[1],  (const float*)d_in[2],
      (const float*)d_in[3],  (const float*)d_in[4],  (const float*)d_in[5],
      (const float*)d_in[6],  (const float*)d_in[7],  (const float*)d_in[8],
      (const float*)d_in[9],  (const float*)d_in[10], (const float*)d_in[11],
      (const float*)d_in[12], (const float*)d_in[13], (const float*)d_in[14],
      (const float*)d_in[15], (const float*)d_in[16], (const float*)d_in[17],
      (const float*)d_in[18], (float*)d_out);
}